// Round 10
// baseline (217.890 us; speedup 1.0000x reference)
//
#include <hip/hip_runtime.h>

// IBNModel: graph-coupled bidirectional GRU + decoder. All fp32 in/out.
// B=16, H=64, N=512, C=3, E=128, D=32, L_OUT=12, LAYERS=2.
//
//  K1 prep      : softmax rows -> row-major AfR/AbR; ufrag/wbfrag (pre-scaled
//                 -log2e / +2log2e); x -> xT16. All stores coalesced.
//  K2 transpose : LDS-tiled 64x64: adj->adjT, AfR->AfT, AbR->AbT.
//  K3 msg       : MFMA GEMM, direct xT16 A-loads; output = 16-lane frag rows
//                 [x0,x1,x2,xa0,xa1,xa2,xf0,xf1] (msgF) + f2 side array
//                 (msgF2); bias row is a constant, built in rec's prologue.
//  K4 rec       : MFMA recurrence (16 cols/block, grid 512, 8 waves,
//                 2 blocks/CU). ALL 64 msg steps (+backward slot 64) staged
//                 in LDS in the prologue -> no global loads / vmcnt in loop.
//                 Split MFMA chains (2+3), u-sigmoid hoisted to interval 1.

typedef _Float16 half8_t __attribute__((ext_vector_type(8)));
typedef __fp16 fp16x2_t __attribute__((ext_vector_type(2)));
typedef float float4_t __attribute__((ext_vector_type(4)));

#define PIN(x) asm volatile("" : "+v"(x))

__device__ __forceinline__ float exp2_(float x) { return __builtin_amdgcn_exp2f(x); }
__device__ __forceinline__ float rcp_(float x) { return __builtin_amdgcn_rcpf(x); }

// ---------------- K1: prep --------------------------------------------------
__global__ __launch_bounds__(256) void prep_kernel(
    const float* __restrict__ E1f, const float* __restrict__ E2f,
    const float* __restrict__ E1b, const float* __restrict__ E2b,
    const float* __restrict__ x, const float* __restrict__ Wf,
    const float* __restrict__ Uf, const float* __restrict__ bf,
    const float* __restrict__ Wb, const float* __restrict__ bb,
    _Float16* __restrict__ AfR, _Float16* __restrict__ AbR,
    _Float16* __restrict__ xT16, _Float16* __restrict__ ufrag,
    _Float16* __restrict__ wbfrag) {
  int bid = blockIdx.x;
  int tid = threadIdx.x;
  if (bid >= 1160) {  // xT16: 1024 blocks, one per (b,t) — coalesced
    int bid2 = bid - 1160;
    int b = bid2 >> 6, t = bid2 & 63;
    const float2* xp = (const float2*)(x + (size_t)(b * 64 + t) * 1536);
    float2 f0 = xp[tid * 3], f1 = xp[tid * 3 + 1], f2 = xp[tid * 3 + 2];
    _Float16* dst = xT16 + (size_t)(b * 64 + t) * 1536;
    int n0_ = tid * 2;
    dst[n0_] = (_Float16)f0.x;
    dst[512 + n0_] = (_Float16)f0.y;
    dst[1024 + n0_] = (_Float16)f1.x;
    dst[n0_ + 1] = (_Float16)f1.y;
    dst[512 + n0_ + 1] = (_Float16)f2.x;
    dst[1024 + n0_ + 1] = (_Float16)f2.y;
    return;
  }
  if (bid >= 1144) {  // wbfrag: 16 regions r2 = og*2 + (gi-1), pre-scaled
    int r2 = bid - 1144;
    int gi = 1 + (r2 & 1);
    int og = r2 >> 1;
    float scl = (gi == 2) ? 2.8853902f : -1.4426950f;
    for (int e = tid; e < 512; e += 256) {
      int lane = e >> 3, j = e & 7;
      int o = og * 16 + (lane & 15);
      int q = (lane >> 4) * 8 + j;
      float v = (q < 9) ? Wb[gi * 1152 + o * 9 + q]
                        : (q == 9 ? bb[gi * 128 + o] : 0.f);
      wbfrag[r2 * 512 + e] = (_Float16)(v * scl);
    }
    return;
  }
  if (bid >= 1024) {  // ufrag: 120 regions r = (og*3+gi)*5+kb, pre-scaled
    int r = bid - 1024;
    int kb = r % 5;
    int gi = (r / 5) % 3;
    int og = r / 15;
    float scl = (gi == 2) ? 2.8853902f : -1.4426950f;
    for (int e = tid; e < 512; e += 256) {
      int lane = e >> 3, j = e & 7;
      int o = og * 16 + (lane & 15);
      int q4 = lane >> 4;
      float v;
      if (kb < 4) {
        v = Uf[gi * 16384 + o * 128 + kb * 32 + q4 * 8 + j];
      } else {
        int q = q4 * 8 + j;
        v = (q < 9) ? Wf[gi * 1152 + o * 9 + q]
                    : (q == 9 ? bf[gi * 128 + o] : 0.f);
      }
      ufrag[r * 512 + e] = (_Float16)(v * scl);
    }
    return;
  }
  // softmax(relu(E1 E2^T)) row -> row-major (coalesced stores)
  int which = bid >> 9;
  int row = bid & 511;
  const float* E1 = which ? E1b : E1f;
  const float* E2 = which ? E2b : E2f;
  _Float16* A = which ? AbR : AfR;
  __shared__ float e1s[32];
  __shared__ float red[256];
  if (tid < 32) e1s[tid] = E1[row * 32 + tid];
  __syncthreads();
  float s[2];
#pragma unroll
  for (int h = 0; h < 2; ++h) {
    int m = tid + h * 256;
    const float4* e2 = (const float4*)(E2 + m * 32);
    float acc = 0.f;
#pragma unroll
    for (int d4 = 0; d4 < 8; ++d4) {
      float4 v = e2[d4];
      acc = fmaf(v.x, e1s[d4 * 4 + 0], acc);
      acc = fmaf(v.y, e1s[d4 * 4 + 1], acc);
      acc = fmaf(v.z, e1s[d4 * 4 + 2], acc);
      acc = fmaf(v.w, e1s[d4 * 4 + 3], acc);
    }
    s[h] = fmaxf(acc, 0.f);
  }
  red[tid] = fmaxf(s[0], s[1]);
  __syncthreads();
  for (int off = 128; off > 0; off >>= 1) {
    if (tid < off) red[tid] = fmaxf(red[tid], red[tid + off]);
    __syncthreads();
  }
  float mx = red[0];
  __syncthreads();
  float e0 = __expf(s[0] - mx), e1v = __expf(s[1] - mx);
  red[tid] = e0 + e1v;
  __syncthreads();
  for (int off = 128; off > 0; off >>= 1) {
    if (tid < off) red[tid] += red[tid + off];
    __syncthreads();
  }
  float inv = rcp_(red[0]);
  A[(size_t)row * 512 + tid] = (_Float16)(e0 * inv);
  A[(size_t)row * 512 + tid + 256] = (_Float16)(e1v * inv);
}

// ---------------- K2: LDS-tiled transposes ----------------------------------
__global__ __launch_bounds__(256) void transpose_kernel(
    const float* __restrict__ adj, const _Float16* __restrict__ AfR,
    const _Float16* __restrict__ AbR, _Float16* __restrict__ adjT,
    _Float16* __restrict__ AfT, _Float16* __restrict__ AbT) {
  __shared__ _Float16 T[64][65];
  int bid = blockIdx.x;
  int mat = bid >> 6;
  int tile = bid & 63;
  int tr = tile >> 3, tc = tile & 7;
  int t = threadIdx.x;
  int r = t >> 2, cb = (t & 3) * 16;
  if (mat == 0) {
    const float* s = adj + (size_t)(tr * 64 + r) * 512 + tc * 64 + cb;
#pragma unroll
    for (int i = 0; i < 16; ++i) T[r][cb + i] = (_Float16)s[i];
  } else {
    const _Float16* s =
        (mat == 1 ? AfR : AbR) + (size_t)(tr * 64 + r) * 512 + tc * 64 + cb;
#pragma unroll
    for (int i = 0; i < 16; ++i) T[r][cb + i] = s[i];
  }
  __syncthreads();
  _Float16* d = (mat == 0 ? adjT : mat == 1 ? AfT : AbT) +
                (size_t)(tc * 64 + r) * 512 + tr * 64 + cb;
#pragma unroll
  for (int i = 0; i < 16; ++i) d[i] = T[cb + i][r];
}

// ---------------- K3: message GEMM -> 16-lane frag rows + f2 side array -----
// grid 1024 = t(64) x nchunk(16, 32 cols); 256 thr = 4 waves (nt, mat).
// msgF[slice=(b*32+gnt)][t][cl 0..15][8]: j0-7 = [x0,x1,x2,a0,a1,a2,f0,f1]
// msgF2[slice][t][cl]: f2.   msgbF/msgb2: same for backward (Ab), t=63.
__global__ __launch_bounds__(256, 4) void msg_kernel(
    const _Float16* __restrict__ xT16, const _Float16* __restrict__ adjT,
    const _Float16* __restrict__ AfT, const _Float16* __restrict__ AbT,
    _Float16* __restrict__ msgF, _Float16* __restrict__ msgF2,
    _Float16* __restrict__ msgbF, _Float16* __restrict__ msgb2) {
  __shared__ __align__(16) _Float16 Sst[32 * 16 * 8];  // 8 KB
  __shared__ __align__(16) _Float16 Sf2[32 * 16];      // 1 KB
  int tid = threadIdx.x;
  int t = blockIdx.x >> 4;
  int nc = blockIdx.x & 15;
  int n0g = nc * 32;
  int lane = tid & 63, og = tid >> 6;
  int l15 = lane & 15, q4 = lane >> 4, q0 = q4 * 8;
  int nt = og & 1, mat = og >> 1;
  bool is63 = (t == 63);
  bool doAb = is63 && (mat == 0);

  const _Float16* Bmat = mat ? AfT : adjT;
  int n = n0g + nt * 16 + l15;

  const float4_t zero4 = {0.f, 0.f, 0.f, 0.f};
  float4_t acc[3], accb[3];
#pragma unroll
  for (int mt = 0; mt < 3; ++mt) { acc[mt] = zero4; accb[mt] = zero4; }

  for (int kb = 0; kb < 16; ++kb) {
    half8_t b0 = *(const half8_t*)&Bmat[(size_t)n * 512 + kb * 32 + q0];
    half8_t b2;
    if (doAb) b2 = *(const half8_t*)&AbT[(size_t)n * 512 + kb * 32 + q0];
#pragma unroll
    for (int mt = 0; mt < 3; ++mt) {
      int m = mt * 16 + l15;
      int bm = (m * 21846) >> 16;
      int cm = m - bm * 3;
      half8_t a = *(const half8_t*)
          &xT16[((size_t)(bm * 64 + t) * 3 + cm) * 512 + kb * 32 + q0];
      acc[mt] = __builtin_amdgcn_mfma_f32_16x16x32_f16(a, b0, acc[mt], 0, 0, 0);
      if (doAb)
        accb[mt] = __builtin_amdgcn_mfma_f32_16x16x32_f16(a, b2, accb[mt], 0, 0, 0);
    }
  }

  // x channels j0-2
  for (int i = tid; i < 512; i += 256) {
    int tb = i >> 5, r = i & 31, nt2 = r >> 4, cl = r & 15;
    int nn = n0g + nt2 * 16 + cl;
    _Float16* row = &Sst[((tb * 2 + nt2) * 16 + cl) * 8];
#pragma unroll
    for (int c = 0; c < 3; ++c)
      row[c] = xT16[((size_t)(tb * 64 + t) * 3 + c) * 512 + nn];
  }
  // MFMA results (C layout: col=l15, row=q4*4+r)
#pragma unroll
  for (int mt = 0; mt < 3; ++mt)
#pragma unroll
    for (int r = 0; r < 4; ++r) {
      int m = mt * 16 + q4 * 4 + r;
      int tb = (m * 21846) >> 16;
      int c = m - tb * 3;
      int sl = tb * 2 + nt;
      if (mat == 0) Sst[(sl * 16 + l15) * 8 + 3 + c] = (_Float16)acc[mt][r];
      else if (c < 2) Sst[(sl * 16 + l15) * 8 + 6 + c] = (_Float16)acc[mt][r];
      else Sf2[sl * 16 + l15] = (_Float16)acc[mt][r];
    }
  __syncthreads();
  for (int i = tid; i < 512; i += 256) {
    int sl = i >> 4, u = i & 15;
    int tb = sl >> 1, nt2 = sl & 1;
    size_t slice = (size_t)tb * 32 + nc * 2 + nt2;
    ((uint4*)msgF)[(slice * 64 + t) * 16 + u] = ((const uint4*)Sst)[i];
  }
  if (tid < 64) {
    int sl = tid >> 1, h = tid & 1;
    int tb = sl >> 1, nt2 = sl & 1;
    size_t slice = (size_t)tb * 32 + nc * 2 + nt2;
    ((uint4*)msgF2)[(slice * 64 + t) * 2 + h] = ((const uint4*)Sf2)[sl * 2 + h];
  }
  if (is63) {
    __syncthreads();  // main copy done before overwrite
    if (mat == 0) {
#pragma unroll
      for (int mt = 0; mt < 3; ++mt)
#pragma unroll
        for (int r = 0; r < 4; ++r) {
          int m = mt * 16 + q4 * 4 + r;
          int tb = (m * 21846) >> 16;
          int c = m - tb * 3;
          int sl = tb * 2 + nt;
          if (c < 2) Sst[(sl * 16 + l15) * 8 + 6 + c] = (_Float16)accb[mt][r];
          else Sf2[sl * 16 + l15] = (_Float16)accb[mt][r];
        }
    }
    __syncthreads();
    for (int i = tid; i < 512; i += 256) {
      int sl = i >> 4, u = i & 15;
      int tb = sl >> 1, nt2 = sl & 1;
      size_t slice = (size_t)tb * 32 + nc * 2 + nt2;
      ((uint4*)msgbF)[slice * 16 + u] = ((const uint4*)Sst)[i];
    }
    if (tid < 64) {
      int sl = tid >> 1, h = tid & 1;
      int tb = sl >> 1, nt2 = sl & 1;
      size_t slice = (size_t)tb * 32 + nc * 2 + nt2;
      ((uint4*)msgb2)[slice * 2 + h] = ((const uint4*)Sf2)[sl * 2 + h];
    }
  }
}

// ---------------- K4: MFMA recurrence + backward + decoder ------------------
// grid 512 = b(16) x ntile(32, 16 cols); 512 thr = 8 waves, 2 blocks/CU.
// All 64 msg steps + backward slot (65) staged in LDS in the prologue.
__global__ __launch_bounds__(512, 4) void rec_kernel(
    const _Float16* __restrict__ msgF, const _Float16* __restrict__ msgF2,
    const _Float16* __restrict__ msgbF, const _Float16* __restrict__ msgb2,
    const _Float16* __restrict__ ufrag, const _Float16* __restrict__ wbfrag,
    const float* __restrict__ dec_w, const float* __restrict__ dec_b,
    const float* __restrict__ out_w, const float* __restrict__ out_b,
    float* __restrict__ out) {
  __shared__ __align__(16) _Float16 Bmsg[65 * 256];  // 32.5 KB [t][lane32][8]
  __shared__ __align__(16) _Float16 Cbuf[2048];      // 4 KB
  __shared__ __align__(16) _Float16 Gbuf[2048];      // 4 KB
  __shared__ float hf_lds[128 * 16];                 // 8 KB
  __shared__ float hb_lds[128 * 16];                 // 8 KB
  __shared__ float hdec_lds[12 * 16];
  int tid = threadIdx.x, bid = blockIdx.x;
  int b = bid >> 5;
  int nt = bid & 31;
  int n0 = nt * 16;
  int lane = tid & 63, og = tid >> 6;
  int l15 = lane & 15, q4 = lane >> 4;
  size_t slice = (size_t)b * 32 + nt;

  half8_t afrag[3][5];
#pragma unroll
  for (int gi = 0; gi < 3; ++gi)
#pragma unroll
    for (int kb = 0; kb < 5; ++kb) {
      afrag[gi][kb] = *(const half8_t*)
          &ufrag[(size_t)(((og * 3 + gi) * 5 + kb) * 512) + lane * 8];
      PIN(afrag[gi][kb]);
    }

  // prologue: stage msg slice into LDS (pre-muxed frag layout)
  {
    const uint4* src = (const uint4*)msgF + slice * 64 * 16;
    uint4 z; z.x = z.y = z.z = z.w = 0;
    for (int f = tid; f < 1024; f += 512) {
      int t = f >> 4, u = f & 15;
      ((uint4*)Bmsg)[t * 32 + u] = src[f];                 // lanes 0-15
      ((uint4*)Bmsg)[t * 32 + 16 + u] = z;                 // lanes 16-31 zero
    }
  }
  if (tid < 16) {
    ((uint4*)Bmsg)[64 * 32 + tid] = ((const uint4*)msgbF)[slice * 16 + tid];
    ((uint4*)Bmsg)[64 * 32 + 16 + tid] = uint4{0, 0, 0, 0};
  }
  if (tid < 256) {
    uint4 z; z.x = z.y = z.z = z.w = 0;
    ((uint4*)Cbuf)[tid] = z;
  }
  __syncthreads();  // zeros visible before scatter of f2/bias
  // f2 + bias row (lanes 16-31, j0=f2, j1=1)
  {
    const _Float16* f2p = msgF2 + slice * 64 * 16;
    for (int f = tid; f < 1024; f += 512) {
      int t = f >> 4, l = f & 15;
      _Float16* d = &Bmsg[(t * 32 + 16 + l) * 8];
      d[0] = f2p[t * 16 + l];
      d[1] = (_Float16)1.f;
    }
    if (tid < 16) {
      _Float16* d = &Bmsg[(64 * 32 + 16 + tid) * 8];
      d[0] = msgb2[slice * 16 + tid];
      d[1] = (_Float16)1.f;
    }
  }
  float cr[4] = {0.f, 0.f, 0.f, 0.f};

  const float4_t zero4 = {0.f, 0.f, 0.f, 0.f};
  union H4U { fp16x2_t h2[2]; unsigned long long u; };
  int kb_w = og >> 1;
  int lane_w = ((og & 1) * 2 + (q4 >> 1)) * 16 + l15;
  int j0 = (q4 & 1) * 4;
  int bm_off = ((lane & 31)) * 8;
  __syncthreads();

  for (int t = 0; t < 64; ++t) {
    half8_t bm = *(const half8_t*)&Bmsg[t * 256 + bm_off];
    half8_t cf[4];
#pragma unroll
    for (int kb = 0; kb < 4; ++kb)
      cf[kb] = *(const half8_t*)&Cbuf[(kb * 64 + lane) * 8];

    // split chains: (kb0,kb1) and (msg,kb2,kb3)
    float4_t accr1 = __builtin_amdgcn_mfma_f32_16x16x32_f16(afrag[0][0], cf[0], zero4, 0, 0, 0);
    float4_t accu1 = __builtin_amdgcn_mfma_f32_16x16x32_f16(afrag[1][0], cf[0], zero4, 0, 0, 0);
    float4_t accr2 = __builtin_amdgcn_mfma_f32_16x16x32_f16(afrag[0][4], bm, zero4, 0, 0, 0);
    float4_t accu2 = __builtin_amdgcn_mfma_f32_16x16x32_f16(afrag[1][4], bm, zero4, 0, 0, 0);
    float4_t accg_p = __builtin_amdgcn_mfma_f32_16x16x32_f16(afrag[2][4], bm, zero4, 0, 0, 0);
    accr1 = __builtin_amdgcn_mfma_f32_16x16x32_f16(afrag[0][1], cf[1], accr1, 0, 0, 0);
    accu1 = __builtin_amdgcn_mfma_f32_16x16x32_f16(afrag[1][1], cf[1], accu1, 0, 0, 0);
    accr2 = __builtin_amdgcn_mfma_f32_16x16x32_f16(afrag[0][2], cf[2], accr2, 0, 0, 0);
    accu2 = __builtin_amdgcn_mfma_f32_16x16x32_f16(afrag[1][2], cf[2], accu2, 0, 0, 0);
    accr2 = __builtin_amdgcn_mfma_f32_16x16x32_f16(afrag[0][3], cf[3], accr2, 0, 0, 0);
    accu2 = __builtin_amdgcn_mfma_f32_16x16x32_f16(afrag[1][3], cf[3], accu2, 0, 0, 0);

    float uu[4];
    {  // r = rcp(1+exp2(.)); rc -> Gbuf; u-sigmoid hoisted here
      float4_t accr = accr1 + accr2;
      float4_t accu = accu1 + accu2;
      H4U v;
#pragma unroll
      for (int r = 0; r < 2; ++r) {
        float a = rcp_(1.f + exp2_(accr[2 * r])) * cr[2 * r];
        float bq = rcp_(1.f + exp2_(accr[2 * r + 1])) * cr[2 * r + 1];
        v.h2[r] = __builtin_amdgcn_cvt_pkrtz(a, bq);
      }
      *(unsigned long long*)&Gbuf[(kb_w * 64 + lane_w) * 8 + j0] = v.u;
#pragma unroll
      for (int r = 0; r < 4; ++r) uu[r] = rcp_(1.f + exp2_(accu[r]));
    }
    __syncthreads();  // rc visible; Cbuf reads done

    half8_t gf[4];
#pragma unroll
    for (int kb = 0; kb < 4; ++kb)
      gf[kb] = *(const half8_t*)&Gbuf[(kb * 64 + lane) * 8];
    float4_t accg1 = __builtin_amdgcn_mfma_f32_16x16x32_f16(afrag[2][0], gf[0], accg_p, 0, 0, 0);
    float4_t accg2 = __builtin_amdgcn_mfma_f32_16x16x32_f16(afrag[2][2], gf[2], zero4, 0, 0, 0);
    accg1 = __builtin_amdgcn_mfma_f32_16x16x32_f16(afrag[2][1], gf[1], accg1, 0, 0, 0);
    accg2 = __builtin_amdgcn_mfma_f32_16x16x32_f16(afrag[2][3], gf[3], accg2, 0, 0, 0);

    {  // g = 1-2*rcp(1+exp2(.)); c update
      float4_t accg = accg1 + accg2;
      H4U v;
      float cn[4];
#pragma unroll
      for (int r = 0; r < 4; ++r) {
        float gg = fmaf(-2.f, rcp_(exp2_(accg[r]) + 1.f), 1.f);
        cn[r] = fmaf(uu[r], cr[r] - gg, gg);  // u*c + (1-u)*g
        cr[r] = cn[r];
      }
      v.h2[0] = __builtin_amdgcn_cvt_pkrtz(cn[0], cn[1]);
      v.h2[1] = __builtin_amdgcn_cvt_pkrtz(cn[2], cn[3]);
      *(unsigned long long*)&Cbuf[(kb_w * 64 + lane_w) * 8 + j0] = v.u;
    }
    __syncthreads();  // c_{t+1} visible; Gbuf reads done
  }

  // backward cell (LDS slot 64): h_back = (1-sig(pre_u))*tanh(pre_g)
  {
    half8_t bbk = *(const half8_t*)&Bmsg[64 * 256 + bm_off];
    half8_t au_f = *(const half8_t*)&wbfrag[(size_t)((og * 2 + 0) * 512) + lane * 8];
    half8_t ag_f = *(const half8_t*)&wbfrag[(size_t)((og * 2 + 1) * 512) + lane * 8];
    float4_t au = __builtin_amdgcn_mfma_f32_16x16x32_f16(au_f, bbk, zero4, 0, 0, 0);
    float4_t ag = __builtin_amdgcn_mfma_f32_16x16x32_f16(ag_f, bbk, zero4, 0, 0, 0);
#pragma unroll
    for (int r = 0; r < 4; ++r) {
      int row = og * 16 + q4 * 4 + r;
      float uu2 = rcp_(1.f + exp2_(au[r]));
      float gg = fmaf(-2.f, rcp_(exp2_(ag[r]) + 1.f), 1.f);
      hb_lds[row * 16 + l15] = (1.f - uu2) * gg;
      hf_lds[row * 16 + l15] = cr[r];
    }
  }
  __syncthreads();

  // decoder
  if (tid < 192) {
    int i = tid >> 4, cc = tid & 15;
    const float* dwa = dec_w + (size_t)i * 512;
    const float* dwb = dwa + 256;
    float hd = dec_b[i];
    for (int e = 0; e < 128; ++e) {
      hd = fmaf(dwa[e] + dwb[e], hf_lds[e * 16 + cc], hd);
      hd = fmaf(dwa[128 + e] + dwb[128 + e], hb_lds[e * 16 + cc], hd);
    }
    hdec_lds[i * 16 + cc] = hd;
  }
  __syncthreads();
  if (tid < 192) {
    int o = tid >> 4, cc = tid & 15;
    float v = out_b[o];
#pragma unroll
    for (int i = 0; i < 12; ++i) v = fmaf(out_w[o * 12 + i], hdec_lds[i * 16 + cc], v);
    out[((size_t)(b * 12 + o)) * 512 + n0 + cc] = v;
  }
}

extern "C" void kernel_launch(void* const* d_in, const int* in_sizes, int n_in,
                              void* d_out, int out_size, void* d_ws, size_t ws_size,
                              hipStream_t stream) {
  (void)in_sizes; (void)n_in; (void)out_size; (void)ws_size;
  const float* x     = (const float*)d_in[0];
  const float* adj   = (const float*)d_in[1];
  const float* Wf    = (const float*)d_in[2];
  const float* Uf    = (const float*)d_in[3];
  const float* bf    = (const float*)d_in[4];
  const float* E1f   = (const float*)d_in[5];
  const float* E2f   = (const float*)d_in[6];
  const float* Wb    = (const float*)d_in[7];
  const float* bb    = (const float*)d_in[9];
  const float* E1b   = (const float*)d_in[10];
  const float* E2b   = (const float*)d_in[11];
  const float* dec_w = (const float*)d_in[12];
  const float* dec_b = (const float*)d_in[13];
  const float* out_w = (const float*)d_in[14];
  const float* out_b = (const float*)d_in[15];

  _Float16* h      = (_Float16*)d_ws;
  _Float16* adjT   = h;                        //   262144
  _Float16* AfT    = h + 262144;               //   262144
  _Float16* AbT    = h + 524288;               //   262144
  _Float16* ufrag  = h + 786432;               //    61440
  _Float16* wbfrag = h + 847872;               //     8192
  _Float16* xT16   = h + 856064;               //  1572864
  _Float16* msgF   = h + 2428928;              //  4194304 (16-lane frag rows)
  _Float16* msgF2  = h + 6623232;              //   524288 (f2 side array)
  _Float16* msgbF  = h + 7147520;              //    65536
  _Float16* msgb2  = h + 7213056;              //     8192
  _Float16* AfR    = msgF;                     //   262144 (temp, overlapped)
  _Float16* AbR    = msgF + 262144;            //   262144 (temp, overlapped)
  // total 7,221,248 halves = 14.4 MB

  prep_kernel<<<2184, 256, 0, stream>>>(E1f, E2f, E1b, E2b, x, Wf, Uf, bf,
                                        Wb, bb, AfR, AbR, xT16, ufrag, wbfrag);
  transpose_kernel<<<192, 256, 0, stream>>>(adj, AfR, AbR, adjT, AfT, AbT);
  msg_kernel<<<1024, 256, 0, stream>>>(xT16, adjT, AfT, AbT, msgF, msgF2,
                                       msgbF, msgb2);
  rec_kernel<<<512, 512, 0, stream>>>(msgF, msgF2, msgbF, msgb2, ufrag, wbfrag,
                                      dec_w, dec_b, out_w, out_b, (float*)d_out);
}

// Round 11
// 200.486 us; speedup vs baseline: 1.0868x; 1.0868x over previous
//
#include <hip/hip_runtime.h>

// IBNModel: graph-coupled bidirectional GRU + decoder. All fp32 in/out.
// B=16, H=64, N=512, C=3, E=128, D=32, L_OUT=12, LAYERS=2.
//
//  K1 prep : softmax(relu(E1 E2^T)) -> fp16 transposed AfT/AbT; adj -> adjT;
//            ufrag/wbfrag pre-scaled (-log2e for r,u / +2log2e for g); zpad.
//  K2 msg  : MFMA GEMM (x staged in XOR-swizzled LDS). Output rows PADDED to
//            32 B: [x0,x1,x2,a0,a1,a2,f0,f1 | f2,1,0,0,0,0,0,0] -> rec's
//            per-step B-frag is ONE aligned b128 (no mux/unpack VALU).
//  K3 rec  : R8 shape (16 cols/block, grid 512, 8 waves, 2 blocks/CU,
//            2 barriers/step), 15 pinned A-frags, exp2 activations, pkrtz
//            packing, u-sigmoid hoisted into the pre-barrier gap.

typedef _Float16 half8_t __attribute__((ext_vector_type(8)));
typedef __fp16 fp16x2_t __attribute__((ext_vector_type(2)));
typedef float float4_t __attribute__((ext_vector_type(4)));

#define PIN(x) asm volatile("" : "+v"(x))

__device__ __forceinline__ float exp2_(float x) { return __builtin_amdgcn_exp2f(x); }
__device__ __forceinline__ float rcp_(float x) { return __builtin_amdgcn_rcpf(x); }

// ---------------- K1: prep --------------------------------------------------
__global__ __launch_bounds__(256) void prep_kernel(
    const float* __restrict__ E1f, const float* __restrict__ E2f,
    const float* __restrict__ E1b, const float* __restrict__ E2b,
    const float* __restrict__ adj, const float* __restrict__ Wf,
    const float* __restrict__ Uf, const float* __restrict__ bf,
    const float* __restrict__ Wb, const float* __restrict__ bb,
    _Float16* __restrict__ adjT, _Float16* __restrict__ AfT,
    _Float16* __restrict__ AbT, _Float16* __restrict__ ufrag,
    _Float16* __restrict__ wbfrag, _Float16* __restrict__ zpad) {
  int bid = blockIdx.x;
  int tid = threadIdx.x;
  if (bid >= 1288) {  // zero pad (16B-aligned zero source for q4>=2 lanes)
    if (tid < 64) zpad[tid] = (_Float16)0.f;
    return;
  }
  if (bid >= 1272) {  // wbfrag: 16 regions r2 = og*2 + (gi-1), pre-scaled
    int r2 = bid - 1272;
    int gi = 1 + (r2 & 1);
    int og = r2 >> 1;
    float scl = (gi == 2) ? 2.8853902f : -1.4426950f;
    for (int e = tid; e < 512; e += 256) {
      int lane = e >> 3, j = e & 7;
      int o = og * 16 + (lane & 15);
      int q = (lane >> 4) * 8 + j;
      float v = (q < 9) ? Wb[gi * 1152 + o * 9 + q]
                        : (q == 9 ? bb[gi * 128 + o] : 0.f);
      wbfrag[r2 * 512 + e] = (_Float16)(v * scl);
    }
    return;
  }
  if (bid >= 1152) {  // ufrag: 120 regions r = (og*3+gi)*5+kb, pre-scaled
    int r = bid - 1152;
    int kb = r % 5;
    int gi = (r / 5) % 3;
    int og = r / 15;
    float scl = (gi == 2) ? 2.8853902f : -1.4426950f;
    for (int e = tid; e < 512; e += 256) {
      int lane = e >> 3, j = e & 7;
      int o = og * 16 + (lane & 15);
      int q4 = lane >> 4;
      float v;
      if (kb < 4) {
        v = Uf[gi * 16384 + o * 128 + kb * 32 + q4 * 8 + j];
      } else {
        int q = q4 * 8 + j;
        v = (q < 9) ? Wf[gi * 1152 + o * 9 + q]
                    : (q == 9 ? bf[gi * 128 + o] : 0.f);
      }
      ufrag[r * 512 + e] = (_Float16)(v * scl);
    }
    return;
  }
  if (bid >= 1024) {  // adj -> adjT fp16 (transpose)
    int base = (bid - 1024) * 4;
    for (int r = 0; r < 4; ++r) {
      int row = base + r;
      float v0 = adj[row * 512 + tid];
      float v1 = adj[row * 512 + tid + 256];
      adjT[(size_t)tid * 512 + row] = (_Float16)v0;
      adjT[(size_t)(tid + 256) * 512 + row] = (_Float16)v1;
    }
    return;
  }
  int which = bid >> 9;
  int row = bid & 511;
  const float* E1 = which ? E1b : E1f;
  const float* E2 = which ? E2b : E2f;
  _Float16* A = which ? AbT : AfT;
  __shared__ float e1s[32];
  __shared__ float red[256];
  if (tid < 32) e1s[tid] = E1[row * 32 + tid];
  __syncthreads();
  float s[2];
#pragma unroll
  for (int h = 0; h < 2; ++h) {
    int m = tid + h * 256;
    const float4* e2 = (const float4*)(E2 + m * 32);
    float acc = 0.f;
#pragma unroll
    for (int d4 = 0; d4 < 8; ++d4) {
      float4 v = e2[d4];
      acc = fmaf(v.x, e1s[d4 * 4 + 0], acc);
      acc = fmaf(v.y, e1s[d4 * 4 + 1], acc);
      acc = fmaf(v.z, e1s[d4 * 4 + 2], acc);
      acc = fmaf(v.w, e1s[d4 * 4 + 3], acc);
    }
    s[h] = fmaxf(acc, 0.f);
  }
  red[tid] = fmaxf(s[0], s[1]);
  __syncthreads();
  for (int off = 128; off > 0; off >>= 1) {
    if (tid < off) red[tid] = fmaxf(red[tid], red[tid + off]);
    __syncthreads();
  }
  float mx = red[0];
  __syncthreads();
  float e0 = __expf(s[0] - mx), e1v = __expf(s[1] - mx);
  red[tid] = e0 + e1v;
  __syncthreads();
  for (int off = 128; off > 0; off >>= 1) {
    if (tid < off) red[tid] += red[tid + off];
    __syncthreads();
  }
  float inv = rcp_(red[0]);
  A[(size_t)tid * 512 + row] = (_Float16)(e0 * inv);
  A[(size_t)(tid + 256) * 512 + row] = (_Float16)(e1v * inv);
}

// ---------------- K2: message GEMM -> padded 32B rows -----------------------
// grid 512 = t(64) x nc(8, 64 cols); 256 thr = 4 waves (og = local n16 tile),
// 2 blocks/CU (80 KB LDS). Row layout (16 halves):
//   j0-2 = x, j3-5 = x@adj, j6-8 = x@Af (f2 at j8!), j9 = 1, j10-15 = 0.
__global__ __launch_bounds__(256, 2) void msg_kernel(
    const float* __restrict__ x, const _Float16* __restrict__ adjT,
    const _Float16* __restrict__ AfT, const _Float16* __restrict__ AbT,
    _Float16* __restrict__ msg16, _Float16* __restrict__ msgb16) {
  __shared__ __align__(16) _Float16 Alds[48 * 512];   // 48 KB
  __shared__ __align__(16) _Float16 Sst[1024 * 16];   // 32 KB
  int tid = threadIdx.x;
  int t = blockIdx.x >> 3;
  int n0g = (blockIdx.x & 7) * 64;
  int lane = tid & 63, og = tid >> 6;
  int l15 = lane & 15, q4 = lane >> 4, q0 = q4 * 8;
  bool is63 = (t == 63);

  // stage x -> Alds[m=b*3+c][k=n], XOR-swizzled (coalesced float4 reads)
  {
    int b = tid >> 4, li = tid & 15;
    const float4* xb = (const float4*)(x + (size_t)(b * 64 + t) * 1536);
#pragma unroll
    for (int k = 0; k < 24; ++k) {
      float4 v = xb[k * 16 + li];
      int j0 = (k * 16 + li) * 4;
#pragma unroll
      for (int e = 0; e < 4; ++e) {
        int j = j0 + e;
        int n = (j * 21846) >> 16;  // exact j/3 for j<2048
        int c = j - n * 3;
        int m = b * 3 + c;
        float val = (e == 0) ? v.x : (e == 1) ? v.y : (e == 2) ? v.z : v.w;
        Alds[m * 512 + ((((n >> 3) ^ (m & 7)) << 3) | (n & 7))] = (_Float16)val;
      }
    }
  }
  __syncthreads();

  const float4_t zero4 = {0.f, 0.f, 0.f, 0.f};
  float4_t acc[3][2], accb[3];
#pragma unroll
  for (int mt = 0; mt < 3; ++mt) { acc[mt][0] = zero4; acc[mt][1] = zero4; accb[mt] = zero4; }

  int n = n0g + og * 16 + l15;
  for (int kb = 0; kb < 16; ++kb) {
    half8_t afr[3];
#pragma unroll
    for (int mt = 0; mt < 3; ++mt) {
      int m = mt * 16 + l15;
      afr[mt] = *(const half8_t*)&Alds[m * 512 + ((((kb * 4 + q4) ^ (m & 7)) << 3))];
    }
    half8_t b0 = *(const half8_t*)&adjT[(size_t)n * 512 + kb * 32 + q0];
    half8_t b1 = *(const half8_t*)&AfT[(size_t)n * 512 + kb * 32 + q0];
#pragma unroll
    for (int mt = 0; mt < 3; ++mt) {
      acc[mt][0] = __builtin_amdgcn_mfma_f32_16x16x32_f16(afr[mt], b0, acc[mt][0], 0, 0, 0);
      acc[mt][1] = __builtin_amdgcn_mfma_f32_16x16x32_f16(afr[mt], b1, acc[mt][1], 0, 0, 0);
    }
    if (is63) {
      half8_t b2 = *(const half8_t*)&AbT[(size_t)n * 512 + kb * 32 + q0];
#pragma unroll
      for (int mt = 0; mt < 3; ++mt)
        accb[mt] = __builtin_amdgcn_mfma_f32_16x16x32_f16(afr[mt], b2, accb[mt], 0, 0, 0);
    }
  }

  // fill x (j0-2), bias (j9), zeros (j10-15)
  for (int i = tid; i < 1024; i += 256) {
    int tb = i >> 6, nl = i & 63;
    int nn = n0g + nl;
    _Float16* row = &Sst[i * 16];
#pragma unroll
    for (int c = 0; c < 3; ++c) {
      int m = tb * 3 + c;
      row[c] = Alds[m * 512 + ((((nn >> 3) ^ (m & 7)) << 3) | (nn & 7))];
    }
    row[9] = (_Float16)1.f;
#pragma unroll
    for (int z = 10; z < 16; ++z) row[z] = (_Float16)0.f;
  }
  // MFMA results (C layout: col=l15, row=q4*4+r)
#pragma unroll
  for (int mt = 0; mt < 3; ++mt)
#pragma unroll
    for (int r = 0; r < 4; ++r) {
      int m = mt * 16 + q4 * 4 + r;
      int tb = (m * 21846) >> 16;
      int c = m - tb * 3;
      _Float16* row = &Sst[(tb * 64 + og * 16 + l15) * 16];
      row[3 + c] = (_Float16)acc[mt][0][r];
      row[6 + c] = (_Float16)acc[mt][1][r];
    }
  __syncthreads();
  // coalesced copy-out: 2 uint4 per row
  for (int i = tid; i < 2048; i += 256) {
    int rrow = i >> 1, h = i & 1;
    int tb = rrow >> 6, nl = rrow & 63;
    ((uint4*)msg16)[(((size_t)(t * 16 + tb) * 512) + n0g + nl) * 2 + h] =
        ((const uint4*)Sst)[i];
  }
  if (is63) {
    __syncthreads();  // copy-out done before overwrite
#pragma unroll
    for (int mt = 0; mt < 3; ++mt)
#pragma unroll
      for (int r = 0; r < 4; ++r) {
        int m = mt * 16 + q4 * 4 + r;
        int tb = (m * 21846) >> 16;
        int c = m - tb * 3;
        Sst[(tb * 64 + og * 16 + l15) * 16 + 6 + c] = (_Float16)accb[mt][r];
      }
    __syncthreads();
    for (int i = tid; i < 2048; i += 256) {
      int rrow = i >> 1, h = i & 1;
      int tb = rrow >> 6, nl = rrow & 63;
      ((uint4*)msgb16)[(((size_t)tb * 512) + n0g + nl) * 2 + h] =
          ((const uint4*)Sst)[i];
    }
  }
}

// ---------------- K3: MFMA recurrence + backward + decoder ------------------
// grid 512 = b(16) x ntile(32, 16 cols); 512 thr = 8 waves, 2 blocks/CU
// (4 waves/SIMD). Wave og owns rows og*16..+15; 15 pinned A-frags.
__global__ __launch_bounds__(512, 4) void rec_kernel(
    const _Float16* __restrict__ msg16, const _Float16* __restrict__ msgb16,
    const _Float16* __restrict__ zpad, const _Float16* __restrict__ ufrag,
    const _Float16* __restrict__ wbfrag, const float* __restrict__ dec_w,
    const float* __restrict__ dec_b, const float* __restrict__ out_w,
    const float* __restrict__ out_b, float* __restrict__ out) {
  __shared__ __align__(16) _Float16 Cbuf[2048];  // 4 KB
  __shared__ __align__(16) _Float16 Gbuf[2048];  // 4 KB
  __shared__ float hf_lds[128 * 16];
  __shared__ float hb_lds[128 * 16];
  __shared__ float hdec_lds[12 * 16];
  int tid = threadIdx.x, bid = blockIdx.x;
  int b = bid >> 5;
  int nt = bid & 31;
  int n0 = nt * 16;
  int lane = tid & 63, og = tid >> 6;
  int l15 = lane & 15, q4 = lane >> 4;

  half8_t afrag[3][5];
#pragma unroll
  for (int gi = 0; gi < 3; ++gi)
#pragma unroll
    for (int kb = 0; kb < 5; ++kb) {
      afrag[gi][kb] = *(const half8_t*)
          &ufrag[(size_t)(((og * 3 + gi) * 5 + kb) * 512) + lane * 8];
      PIN(afrag[gi][kb]);
    }

  if (tid < 256) {
    uint4 z; z.x = z.y = z.z = z.w = 0;
    ((uint4*)Cbuf)[tid] = z;
  }
  float cr[4] = {0.f, 0.f, 0.f, 0.f};

  const float4_t zero4 = {0.f, 0.f, 0.f, 0.f};
  union H4U { fp16x2_t h2[2]; unsigned long long u; };
  // padded-row message stream: one aligned b128 per step, no mux.
  // lanes q4>=2 (k=16-31, all-zero rows) read the 16B zero pad.
  const char* base = (const char*)msg16 +
                     ((size_t)(b * 512 + n0 + l15)) * 32 + (q4 & 1) * 16;
  const char* mrow = (q4 < 2) ? base : (const char*)zpad;
  size_t tstr = (q4 < 2) ? (size_t)16 * 512 * 32 : 0;
  half8_t bm = *(const half8_t*)mrow;  // t=0

  int kb_w = og >> 1;
  int lane_w = ((og & 1) * 2 + (q4 >> 1)) * 16 + l15;
  int j0 = (q4 & 1) * 4;
  __syncthreads();

  for (int t = 0; t < 64; ++t) {
    // prefetch next step's frag (single b128)
    int tn = (t < 63) ? t + 1 : 63;
    half8_t bm_n = *(const half8_t*)(mrow + (size_t)tn * tstr);

    half8_t cf[4];
#pragma unroll
    for (int kb = 0; kb < 4; ++kb)
      cf[kb] = *(const half8_t*)&Cbuf[(kb * 64 + lane) * 8];

    float4_t accr = zero4, accu = zero4;
#pragma unroll
    for (int kb = 0; kb < 4; ++kb) {
      accr = __builtin_amdgcn_mfma_f32_16x16x32_f16(afrag[0][kb], cf[kb], accr, 0, 0, 0);
      accu = __builtin_amdgcn_mfma_f32_16x16x32_f16(afrag[1][kb], cf[kb], accu, 0, 0, 0);
    }
    accr = __builtin_amdgcn_mfma_f32_16x16x32_f16(afrag[0][4], bm, accr, 0, 0, 0);
    accu = __builtin_amdgcn_mfma_f32_16x16x32_f16(afrag[1][4], bm, accu, 0, 0, 0);
    float4_t accg_p = __builtin_amdgcn_mfma_f32_16x16x32_f16(afrag[2][4], bm, zero4, 0, 0, 0);

    float uu[4];
    {  // r = rcp(1+exp2(.)) [pre-scaled -log2e]; rc -> Gbuf; u hoisted
      H4U v;
#pragma unroll
      for (int r = 0; r < 2; ++r) {
        float a = rcp_(1.f + exp2_(accr[2 * r])) * cr[2 * r];
        float bq = rcp_(1.f + exp2_(accr[2 * r + 1])) * cr[2 * r + 1];
        v.h2[r] = __builtin_amdgcn_cvt_pkrtz(a, bq);
      }
      *(unsigned long long*)&Gbuf[(kb_w * 64 + lane_w) * 8 + j0] = v.u;
#pragma unroll
      for (int r = 0; r < 4; ++r) uu[r] = rcp_(1.f + exp2_(accu[r]));
    }
    __syncthreads();  // rc visible; Cbuf reads done

    half8_t gf[4];
#pragma unroll
    for (int kb = 0; kb < 4; ++kb)
      gf[kb] = *(const half8_t*)&Gbuf[(kb * 64 + lane) * 8];
    float4_t accg = accg_p;
#pragma unroll
    for (int kb = 0; kb < 4; ++kb)
      accg = __builtin_amdgcn_mfma_f32_16x16x32_f16(afrag[2][kb], gf[kb], accg, 0, 0, 0);

    {  // g = 1-2*rcp(1+exp2(.)) [pre-scaled +2log2e]; c update
      H4U v;
      float cn[4];
#pragma unroll
      for (int r = 0; r < 4; ++r) {
        float gg = fmaf(-2.f, rcp_(exp2_(accg[r]) + 1.f), 1.f);
        cn[r] = fmaf(uu[r], cr[r] - gg, gg);  // u*c + (1-u)*g
        cr[r] = cn[r];
      }
      v.h2[0] = __builtin_amdgcn_cvt_pkrtz(cn[0], cn[1]);
      v.h2[1] = __builtin_amdgcn_cvt_pkrtz(cn[2], cn[3]);
      *(unsigned long long*)&Cbuf[(kb_w * 64 + lane_w) * 8 + j0] = v.u;
    }
    __syncthreads();  // c_{t+1} visible; Gbuf reads done
    bm = bm_n;
  }

  // backward cell at t=63, c0=0: h_back = (1-sig(pre_u))*tanh(pre_g)
  {
    const char* bb_base = (const char*)msgb16 +
                          ((size_t)(b * 512 + n0 + l15)) * 32 + (q4 & 1) * 16;
    const char* bp = (q4 < 2) ? bb_base : (const char*)zpad;
    half8_t bbk = *(const half8_t*)bp;
    half8_t au_f = *(const half8_t*)&wbfrag[(size_t)((og * 2 + 0) * 512) + lane * 8];
    half8_t ag_f = *(const half8_t*)&wbfrag[(size_t)((og * 2 + 1) * 512) + lane * 8];
    float4_t au = __builtin_amdgcn_mfma_f32_16x16x32_f16(au_f, bbk, zero4, 0, 0, 0);
    float4_t ag = __builtin_amdgcn_mfma_f32_16x16x32_f16(ag_f, bbk, zero4, 0, 0, 0);
#pragma unroll
    for (int r = 0; r < 4; ++r) {
      int row = og * 16 + q4 * 4 + r;
      float uu2 = rcp_(1.f + exp2_(au[r]));
      float gg = fmaf(-2.f, rcp_(exp2_(ag[r]) + 1.f), 1.f);
      hb_lds[row * 16 + l15] = (1.f - uu2) * gg;
      hf_lds[row * 16 + l15] = cr[r];
    }
  }
  __syncthreads();

  // decoder
  if (tid < 192) {
    int i = tid >> 4, cc = tid & 15;
    const float* dwa = dec_w + (size_t)i * 512;
    const float* dwb = dwa + 256;
    float hd = dec_b[i];
    for (int e = 0; e < 128; ++e) {
      hd = fmaf(dwa[e] + dwb[e], hf_lds[e * 16 + cc], hd);
      hd = fmaf(dwa[128 + e] + dwb[128 + e], hb_lds[e * 16 + cc], hd);
    }
    hdec_lds[i * 16 + cc] = hd;
  }
  __syncthreads();
  if (tid < 192) {
    int o = tid >> 4, cc = tid & 15;
    float v = out_b[o];
#pragma unroll
    for (int i = 0; i < 12; ++i) v = fmaf(out_w[o * 12 + i], hdec_lds[i * 16 + cc], v);
    out[((size_t)(b * 12 + o)) * 512 + n0 + cc] = v;
  }
}

extern "C" void kernel_launch(void* const* d_in, const int* in_sizes, int n_in,
                              void* d_out, int out_size, void* d_ws, size_t ws_size,
                              hipStream_t stream) {
  (void)in_sizes; (void)n_in; (void)out_size; (void)ws_size;
  const float* x     = (const float*)d_in[0];
  const float* adj   = (const float*)d_in[1];
  const float* Wf    = (const float*)d_in[2];
  const float* Uf    = (const float*)d_in[3];
  const float* bf    = (const float*)d_in[4];
  const float* E1f   = (const float*)d_in[5];
  const float* E2f   = (const float*)d_in[6];
  const float* Wb    = (const float*)d_in[7];
  const float* bb    = (const float*)d_in[9];
  const float* E1b   = (const float*)d_in[10];
  const float* E2b   = (const float*)d_in[11];
  const float* dec_w = (const float*)d_in[12];
  const float* dec_b = (const float*)d_in[13];
  const float* out_w = (const float*)d_in[14];
  const float* out_b = (const float*)d_in[15];

  _Float16* h      = (_Float16*)d_ws;
  _Float16* adjT   = h;                        //   262144
  _Float16* AfT    = h + 262144;               //   262144
  _Float16* AbT    = h + 524288;               //   262144
  _Float16* ufrag  = h + 786432;               //    61440
  _Float16* wbfrag = h + 847872;               //     8192
  _Float16* zpad   = h + 856064;               //       64
  _Float16* msg16  = h + 856128;               //  8388608 (32B rows)
  _Float16* msgb16 = h + 9244736;              //   131072
  // total 9,375,808 halves ≈ 18.75 MB

  prep_kernel<<<1289, 256, 0, stream>>>(E1f, E2f, E1b, E2b, adj, Wf, Uf, bf,
                                        Wb, bb, adjT, AfT, AbT, ufrag, wbfrag, zpad);
  msg_kernel<<<512, 256, 0, stream>>>(x, adjT, AfT, AbT, msg16, msgb16);
  rec_kernel<<<512, 512, 0, stream>>>(msg16, msgb16, zpad, ufrag, wbfrag,
                                      dec_w, dec_b, out_w, out_b, (float*)d_out);
}